// Round 10
// baseline (47.436 us; speedup 1.0000x reference)
//
#include <hip/hip_runtime.h>
#include <stdint.h>

#define BB 64
#define NC 1000       // customers per instance
#define KC 10         // clusters
#define MAXR 512      // routes per instance upper bound (realistic max ~140)
#define WPI 4         // blocks per instance
#define BLK 512       // threads per block: 8 waves = 2 waves/SIMD at 1 block/CU
#define NW (BLK / 64) // 8 waves
#define GPI (WPI * (BLK / 16))  // 16-lane NN groups per instance = 128

__host__ __device__ inline void threefry2x32(uint32_t k0, uint32_t k1,
                                             uint32_t x0, uint32_t x1,
                                             uint32_t* o0, uint32_t* o1) {
  uint32_t k2 = k0 ^ k1 ^ 0x1BD11BDAu;
  x0 += k0; x1 += k1;
#define TF_R(R) { x0 += x1; x1 = (x1 << (R)) | (x1 >> (32 - (R))); x1 ^= x0; }
  TF_R(13) TF_R(15) TF_R(26) TF_R(6)
  x0 += k1; x1 += k2 + 1u;
  TF_R(17) TF_R(29) TF_R(16) TF_R(24)
  x0 += k2; x1 += k0 + 2u;
  TF_R(13) TF_R(15) TF_R(26) TF_R(6)
  x0 += k0; x1 += k1 + 3u;
  TF_R(17) TF_R(29) TF_R(16) TF_R(24)
  x0 += k1; x1 += k2 + 4u;
  TF_R(13) TF_R(15) TF_R(26) TF_R(6)
  x0 += k2; x1 += k0 + 5u;
#undef TF_R
  *o0 = x0; *o1 = x1;
}

__device__ inline uint32_t rand_bits(uint32_t ks0, uint32_t ks1, uint32_t p) {
  uint32_t a, b; threefry2x32(ks0, ks1, 0u, p, &a, &b); return b;
}

// DPP 16-lane argmin butterfly step (each 16-lane group = one DPP row,
// branch-uniform -> all source lanes active). All state in named registers.
template <int CTRL>
__device__ __forceinline__ void dpp_min_step(unsigned long long& comb,
                                             float& x, float& y) {
  int lo = (int)(uint32_t)comb;
  int hi = (int)(uint32_t)(comb >> 32);
  int olo = __builtin_amdgcn_update_dpp(lo, lo, CTRL, 0xf, 0xf, false);
  int ohi = __builtin_amdgcn_update_dpp(hi, hi, CTRL, 0xf, 0xf, false);
  int oxi = __builtin_amdgcn_update_dpp(__float_as_int(x), __float_as_int(x),
                                        CTRL, 0xf, 0xf, false);
  int oyi = __builtin_amdgcn_update_dpp(__float_as_int(y), __float_as_int(y),
                                        CTRL, 0xf, 0xf, false);
  unsigned long long o =
      ((unsigned long long)(uint32_t)ohi << 32) | (uint32_t)olo;
  if (o < comb) { comb = o; x = __int_as_float(oxi); y = __int_as_float(oyi); }
}

// ---------------------------------------------------------------------------
// Single fused kernel. __launch_bounds__(BLK, 2): 2 waves/EU declared ->
// VGPR budget ~256/wave -> the ~100-reg working set stays register-resident
// (rounds 7-9 spilled everything at default budget: VGPR_Count 24-40).
// 4 blocks per instance; last-block finalize via device-scope atomic.
// ---------------------------------------------------------------------------
__global__ __launch_bounds__(BLK, 2) void k_all(
    const float* __restrict__ logits,    // (64,1001,10)
    const float* __restrict__ coords,    // (64,1001,2)
    const float* __restrict__ demands,   // (64,1001)
    const float* __restrict__ capacity,  // (64,)
    uint32_t ks0, uint32_t ks1,
    double* __restrict__ pdist,          // (256,) per-block partials
    double* __restrict__ lp,             // (64,)
    int* __restrict__ counter,           // (1,) zeroed before launch
    float* __restrict__ out) {           // (2,)
  int b = blockIdx.x >> 2;               // instance
  int sb = blockIdx.x & 3;               // sub-block within instance
  int tid = threadIdx.x;
  int lane = tid & 63, wv = tid >> 6;    // wave id 0..7
  const float TINY = 1.1754943508222875e-38f;

  __shared__ uint8_t sa[NC];
  __shared__ float memx[NC], memy[NC], memd[NC];
  __shared__ uint16_t rs_[NC], rl_[NC];
  __shared__ uint32_t grt[MAXR];
  __shared__ int wsum[NW][KC];           // per-wave per-cluster chunk counts
  __shared__ int woff[NW][KC];           // per-wave scatter bases
  __shared__ int mc[KC], mbase[KC], rc[KC], rbase[KC];
  __shared__ int rtot_s;
  __shared__ int is_last;
  __shared__ double dred[NW];

  // ---- entry loads for the grouping chunk (latency hides under sampling) --
  const float* cb = coords + (size_t)b * 1001 * 2;
  int i0 = tid * 4;
  bool valid = (i0 < NC);                // threads 250..511 idle in grouping
  float x0f = 0, y0f = 0, d0f = 0, x1f = 0, y1f = 0, d1f = 0;
  float x2f = 0, y2f = 0, d2f = 0, x3f = 0, y3f = 0, d3f = 0;
  if (valid) {
    const float* db = demands + (size_t)b * 1001;
    const float2* cb2 = reinterpret_cast<const float2*>(cb);  // 8B-aligned
    float2 c0 = cb2[i0 + 1], c1 = cb2[i0 + 2], c2 = cb2[i0 + 3], c3 = cb2[i0 + 4];
    x0f = c0.x; y0f = c0.y; d0f = db[i0 + 1];
    x1f = c1.x; y1f = c1.y; d1f = db[i0 + 2];
    x2f = c2.x; y2f = c2.y; d2f = db[i0 + 3];
    x3f = c3.x; y3f = c3.y; d3f = db[i0 + 4];
  }
  float cap = capacity[b];
  float dx0 = cb[0], dy0 = cb[1];

  // ---- phase S: sampling + logprob. Math byte-identical to prior rounds;
  //      xs loaded as 5x float2 (rows are 40B -> 8B aligned), all static idx.
  double lacc = 0.0;
  for (int n = tid; n < NC; n += BLK) {
    const float2* lrow2 = reinterpret_cast<const float2*>(
        logits + ((size_t)b * 1001 + (size_t)(n + 1)) * KC);
    float xs[KC];
    {
      float2 p0 = lrow2[0], p1 = lrow2[1], p2 = lrow2[2], p3 = lrow2[3],
             p4 = lrow2[4];
      xs[0] = p0.x; xs[1] = p0.y; xs[2] = p1.x; xs[3] = p1.y;
      xs[4] = p2.x; xs[5] = p2.y; xs[6] = p3.x; xs[7] = p3.y;
      xs[8] = p4.x; xs[9] = p4.y;
    }
    uint32_t pbase = (uint32_t)(b * NC + n) * (uint32_t)KC;
    int best_k = 0;
    float best_v = -INFINITY;
    float best_x = xs[0];
    float xmax = -INFINITY;
#pragma unroll
    for (int k = 0; k < KC; ++k) {
      uint32_t bits = rand_bits(ks0, ks1, pbase + (uint32_t)k);
      float f = __uint_as_float((bits >> 9) | 0x3f800000u) - 1.0f;
      float u = (f > 0.0f) ? f : TINY;
      float g = -logf(-logf(u));
      float v = g + xs[k];
      if (v > best_v) { best_v = v; best_k = k; best_x = xs[k]; }  // static idx
      xmax = fmaxf(xmax, xs[k]);
    }
    float s = 0.0f;
#pragma unroll
    for (int k = 0; k < KC; ++k) s += expf(xs[k] - xmax);
    float slpv = (best_x - xmax) - logf(s);
    lacc += (double)slpv;
    sa[n] = (uint8_t)best_k;
  }
  // lp: wave butterfly + cross-wave partials
  {
    double t = lacc;
#pragma unroll
    for (int m = 1; m < 64; m <<= 1) t += __shfl_xor(t, m);
    if (lane == 0) dred[wv] = t;
  }
  __syncthreads();                       // publishes sa[] + dred
  if (tid == 0 && sb == 0) {
    double t = 0.0;
    for (int w = 0; w < NW; ++w) t += dred[w];
    lp[b] = t;
  }

  // ---- phase P: chunk assignments from LDS, per-cluster wave scans ----
  int a0 = 0xFF, a1 = 0xFF, a2 = 0xFF, a3 = 0xFF;
  if (valid) { a0 = sa[i0]; a1 = sa[i0 + 1]; a2 = sa[i0 + 2]; a3 = sa[i0 + 3]; }
  int cnt[KC], excl[KC];
#pragma unroll
  for (int k = 0; k < KC; ++k)
    cnt[k] = (a0 == k) + (a1 == k) + (a2 == k) + (a3 == k);
#pragma unroll
  for (int k = 0; k < KC; ++k) {
    int x = cnt[k];
#pragma unroll
    for (int off = 1; off < 64; off <<= 1) {
      int v = __shfl_up(x, off);
      if (lane >= off) x += v;
    }
    if (lane == 63) wsum[wv][k] = x;
    excl[k] = x - cnt[k];                // exclusive rank within wave
  }
  __syncthreads();
  if (tid < KC) {
    int s = 0;
    for (int w = 0; w < NW; ++w) s += wsum[w][tid];
    mc[tid] = s;
  }
  __syncthreads();
  if (tid == 0) {
    int s = 0;
    for (int k = 0; k < KC; ++k) { mbase[k] = s; s += mc[k]; }
  }
  __syncthreads();
  if (tid < NW * KC) {
    int w = tid / KC, k = tid - w * KC;
    int s = mbase[k];
    for (int w2 = 0; w2 < w; ++w2) s += wsum[w2][k];
    woff[w][k] = s;
  }
  __syncthreads();

  // ---- stable scatter into member order ----
  if (valid) {
#pragma unroll
    for (int k = 0; k < KC; ++k) {
      int pos = woff[wv][k] + excl[k];
      if (a0 == k) { memx[pos] = x0f; memy[pos] = y0f; memd[pos] = d0f; pos++; }
      if (a1 == k) { memx[pos] = x1f; memy[pos] = y1f; memd[pos] = d1f; pos++; }
      if (a2 == k) { memx[pos] = x2f; memy[pos] = y2f; memd[pos] = d2f; pos++; }
      if (a3 == k) { memx[pos] = x3f; memy[pos] = y3f; memd[pos] = d3f; pos++; }
    }
  }
  __syncthreads();

  // ---- capacity split per cluster (exact f32 scan semantics) ----
  if (tid < KC) {
    int base = mbase[tid], M = mc[tid];
    int r = 0, cur = 0;
    float load = 0.0f;
    bool ne = false;
    for (int j0 = 0; j0 < M; j0 += 4) {
      float dd0 = memd[base + j0];
      float dd1 = (j0 + 1 < M) ? memd[base + j0 + 1] : 0.0f;
      float dd2 = (j0 + 2 < M) ? memd[base + j0 + 2] : 0.0f;
      float dd3 = (j0 + 3 < M) ? memd[base + j0 + 3] : 0.0f;
#define SPLIT_STEP(dd, jj)                                                    \
      if (j0 + jj < M) {                                                      \
        float d = dd;                                                         \
        if (ne && (load + d > cap)) {                                         \
          rs_[base + r] = (uint16_t)cur; rl_[base + r] = (uint16_t)(j0 + jj - cur); \
          r++; cur = j0 + jj; load = d;                                       \
        } else load += d;                                                     \
        ne = true;                                                            \
      }
      SPLIT_STEP(dd0, 0) SPLIT_STEP(dd1, 1) SPLIT_STEP(dd2, 2) SPLIT_STEP(dd3, 3)
#undef SPLIT_STEP
    }
    if (ne) { rs_[base + r] = (uint16_t)cur; rl_[base + r] = (uint16_t)(M - cur); r++; }
    rc[tid] = r;
  }
  __syncthreads();
  if (tid == 0) {
    int s = 0;
    for (int k = 0; k < KC; ++k) { rbase[k] = s; s += rc[k]; }
    rtot_s = (s < MAXR) ? s : MAXR;
  }
  __syncthreads();

  // ---- compact route table into LDS ----
  if (tid < KC) {
    int k = tid, base = mbase[k];
    for (int r = 0; r < rc[k]; ++r) {
      int slot = rbase[k] + r;
      if (slot < MAXR)
        grt[slot] =
            ((uint32_t)(base + rs_[base + r]) << 16) | (uint32_t)rl_[base + r];
    }
  }
  __syncthreads();

  // ---- phase NN: one 16-lane group per route (<=1 route per group) ----
  int lane16 = tid & 15;
  int g = sb * (BLK / 16) + (tid >> 4);
  int R = rtot_s;
  double gacc = 0.0;

  for (int r = g; r < R; r += GPI) {
    uint32_t pk = grt[r];
    int start = (int)(pk >> 16);
    int L = (int)(pk & 0xFFFFu);

    float mx0 = 0, my0 = 0, mx1 = 0, my1 = 0, mx2 = 0, my2 = 0, mx3 = 0, my3 = 0;
    uint32_t vis = 0;
#define LOADC(c, MX, MY)                                                      \
    { int s = (c) * 16 + lane16;                                              \
      if (s < L) { MX = memx[start + s]; MY = memy[start + s]; }              \
      else vis |= (1u << (c)); }
    LOADC(0, mx0, my0) LOADC(1, mx1, my1) LOADC(2, mx2, my2) LOADC(3, mx3, my3)
#undef LOADC

    float px = dx0, py = dy0, racc = 0.0f;
    for (int step = 0; step < L; ++step) {
      float bd = INFINITY; int bc = -1; float bx = 0, by = 0;
#define CAND(c, MX, MY)                                                       \
      if (!(vis & (1u << (c)))) {                                             \
        float ddx = MX - px, ddy = MY - py;                                   \
        float d = sqrtf(ddx * ddx + ddy * ddy);                               \
        if (d < bd) { bd = d; bc = (c); bx = MX; by = MY; }                   \
      }
      CAND(0, mx0, my0) CAND(1, mx1, my1) CAND(2, mx2, my2) CAND(3, mx3, my3)
#undef CAND
      unsigned long long comb = (bc < 0)
          ? ~0ull
          : (((unsigned long long)__float_as_uint(bd)) << 32) |
            (unsigned)(bc * 16 + lane16);
      dpp_min_step<0xB1>(comb, bx, by);    // lane^1
      dpp_min_step<0x4E>(comb, bx, by);    // lane^2
      dpp_min_step<0x141>(comb, bx, by);   // half mirror
      dpp_min_step<0x140>(comb, bx, by);   // mirror
      int slot = (int)(comb & 0xFFFFFFFFull);
      float best = __uint_as_float((uint32_t)(comb >> 32));
      int src16 = slot & 15, cu = slot >> 4;
      if (src16 == lane16) vis |= (1u << cu);
      px = bx; py = by;
      racc += best;                        // f32, reference scan order
    }
    float ddx = px - dx0, ddy = py - dy0;
    racc += sqrtf(ddx * ddx + ddy * ddy);  // return-to-depot leg
    gacc += (double)racc;                  // racc uniform across group
  }

  // ---- block partial sum (wave butterfly + cross-wave, deterministic) ----
  {
    double t = (lane16 == 0) ? gacc : 0.0;
#pragma unroll
    for (int m = 1; m < 64; m <<= 1) t += __shfl_xor(t, m);
    if (lane == 0) dred[wv] = t;
  }
  __syncthreads();
  if (tid == 0) {
    double t = 0.0;
    for (int w = 0; w < NW; ++w) t += dred[w];
    pdist[blockIdx.x] = t;
  }

  // ---- last-block finalize (device-scope release/acquire, proven r7-r9) --
  if (tid == 0) {
    __threadfence();                       // release pdist/lp stores
    int old = atomicAdd(counter, 1);       // device-scope by default
    __threadfence();
    is_last = (old == (int)gridDim.x - 1);
  }
  __syncthreads();
  if (is_last) {
    __threadfence();                       // acquire on reading threads
    if (tid < 64) {
      double dd = pdist[4 * tid] + pdist[4 * tid + 1] +
                  pdist[4 * tid + 2] + pdist[4 * tid + 3];
      float df = (float)dd;
      float lf = (float)lp[tid];
      double m = (double)df;
#pragma unroll
      for (int m2 = 1; m2 < 64; m2 <<= 1) m += __shfl_xor(m, m2);
      double mean = m / 64.0;
      float meanf = (float)mean;
      double li = ((double)df - (double)meanf) * (double)lf;
#pragma unroll
      for (int m2 = 1; m2 < 64; m2 <<= 1) li += __shfl_xor(li, m2);
      if (tid == 0) {
        out[0] = (float)(li / 64.0);
        out[1] = meanf;
      }
    }
  }
}

extern "C" void kernel_launch(void* const* d_in, const int* in_sizes, int n_in,
                              void* d_out, int out_size, void* d_ws, size_t ws_size,
                              hipStream_t stream) {
  const float* logits   = (const float*)d_in[0];  // (64,1001,10)
  const float* coords   = (const float*)d_in[1];  // (64,1001,2)
  const float* demands  = (const float*)d_in[2];  // (64,1001)
  const float* capacity = (const float*)d_in[3];  // (64,)

  uint8_t* ws = (uint8_t*)d_ws;
  double* pdist   = (double*)(ws);           // 2048 B
  double* lp      = (double*)(ws + 2048);    // 512 B
  int*    counter = (int*)(ws + 2560);       // 4 B (zeroed every call)

  uint32_t ks0, ks1;
  threefry2x32(0u, 42u, 0u, 0u, &ks0, &ks1);   // fold_in(key(42), 0)

  hipMemsetAsync(counter, 0, sizeof(int), stream);
  k_all<<<dim3(BB * WPI), dim3(BLK), 0, stream>>>(
      logits, coords, demands, capacity, ks0, ks1,
      pdist, lp, counter, (float*)d_out);
}

// Round 11
// 44.637 us; speedup vs baseline: 1.0627x; 1.0627x over previous
//
#include <hip/hip_runtime.h>
#include <stdint.h>

#define BB 64
#define NC 1000       // customers per instance
#define KC 10         // clusters
#define MAXR 512      // routes per instance upper bound (realistic max ~140)
#define WPI 4         // blocks per instance in fused kernel
#define BLK 512       // threads per block in fused kernel (8 waves)
#define NW (BLK / 64)
#define GPI (WPI * (BLK / 16))  // 16-lane NN groups per instance = 128

__host__ __device__ inline void threefry2x32(uint32_t k0, uint32_t k1,
                                             uint32_t x0, uint32_t x1,
                                             uint32_t* o0, uint32_t* o1) {
  uint32_t k2 = k0 ^ k1 ^ 0x1BD11BDAu;
  x0 += k0; x1 += k1;
#define TF_R(R) { x0 += x1; x1 = (x1 << (R)) | (x1 >> (32 - (R))); x1 ^= x0; }
  TF_R(13) TF_R(15) TF_R(26) TF_R(6)
  x0 += k1; x1 += k2 + 1u;
  TF_R(17) TF_R(29) TF_R(16) TF_R(24)
  x0 += k2; x1 += k0 + 2u;
  TF_R(13) TF_R(15) TF_R(26) TF_R(6)
  x0 += k0; x1 += k1 + 3u;
  TF_R(17) TF_R(29) TF_R(16) TF_R(24)
  x0 += k1; x1 += k2 + 4u;
  TF_R(13) TF_R(15) TF_R(26) TF_R(6)
  x0 += k2; x1 += k0 + 5u;
#undef TF_R
  *o0 = x0; *o1 = x1;
}

__device__ inline uint32_t rand_bits(uint32_t ks0, uint32_t ks1, uint32_t p) {
  uint32_t a, b; threefry2x32(ks0, ks1, 0u, p, &a, &b); return b;
}

// DPP 16-lane argmin butterfly step (each 16-lane group = one DPP row,
// branch-uniform -> all source lanes active).
template <int CTRL>
__device__ __forceinline__ void dpp_min_step(unsigned long long& comb,
                                             float& x, float& y) {
  int lo = (int)(uint32_t)comb;
  int hi = (int)(uint32_t)(comb >> 32);
  int olo = __builtin_amdgcn_update_dpp(lo, lo, CTRL, 0xf, 0xf, false);
  int ohi = __builtin_amdgcn_update_dpp(hi, hi, CTRL, 0xf, 0xf, false);
  int oxi = __builtin_amdgcn_update_dpp(__float_as_int(x), __float_as_int(x),
                                        CTRL, 0xf, 0xf, false);
  int oyi = __builtin_amdgcn_update_dpp(__float_as_int(y), __float_as_int(y),
                                        CTRL, 0xf, 0xf, false);
  unsigned long long o =
      ((unsigned long long)(uint32_t)ohi << 32) | (uint32_t)olo;
  if (o < comb) { comb = o; x = __int_as_float(oxi); y = __int_as_float(oyi); }
}

// ---------------------------------------------------------------------------
// Kernel S: one thread per customer, NO redundancy (the r7-r10 fusion ran
// sampling 4x per instance — the dominant VALU+transcendental cost).
// Math byte-identical to all passing rounds.
// ---------------------------------------------------------------------------
__global__ __launch_bounds__(256) void k_sample(
    const float* __restrict__ logits,   // (64,1001,10)
    uint32_t ks0, uint32_t ks1,
    uint8_t* __restrict__ assign,       // (64,1000)
    float* __restrict__ slp) {          // (64,1000)
  int gid = blockIdx.x * 256 + threadIdx.x;
  if (gid >= BB * NC) return;
  int b = gid / NC, n = gid - b * NC;
  const float TINY = 1.1754943508222875e-38f;

  const float2* lrow2 = reinterpret_cast<const float2*>(
      logits + ((size_t)b * 1001 + (size_t)(n + 1)) * KC);
  float xs[KC];
  {
    float2 p0 = lrow2[0], p1 = lrow2[1], p2 = lrow2[2], p3 = lrow2[3],
           p4 = lrow2[4];
    xs[0] = p0.x; xs[1] = p0.y; xs[2] = p1.x; xs[3] = p1.y;
    xs[4] = p2.x; xs[5] = p2.y; xs[6] = p3.x; xs[7] = p3.y;
    xs[8] = p4.x; xs[9] = p4.y;
  }
  uint32_t pbase = (uint32_t)gid * (uint32_t)KC;
  int best_k = 0;
  float best_v = -INFINITY;
  float best_x = xs[0];
  float xmax = -INFINITY;
#pragma unroll
  for (int k = 0; k < KC; ++k) {
    uint32_t bits = rand_bits(ks0, ks1, pbase + (uint32_t)k);
    float f = __uint_as_float((bits >> 9) | 0x3f800000u) - 1.0f;
    float u = (f > 0.0f) ? f : TINY;
    float g = -logf(-logf(u));
    float v = g + xs[k];
    if (v > best_v) { best_v = v; best_k = k; best_x = xs[k]; }  // static idx
    xmax = fmaxf(xmax, xs[k]);
  }
  float s = 0.0f;
#pragma unroll
  for (int k = 0; k < KC; ++k) s += expf(xs[k] - xmax);
  slp[gid] = (best_x - xmax) - logf(s);
  assign[gid] = (uint8_t)best_k;
}

// ---------------------------------------------------------------------------
// Kernel F: grouping + capacity split + NN + partials + last-block finalize.
// 4 blocks/instance x 512 threads (redundant prep is cheap; sampling is not
// redundant anymore). Same phase code as r10 (passing, absmax 2.5).
// ---------------------------------------------------------------------------
__global__ __launch_bounds__(BLK) void k_fused(
    const float* __restrict__ coords,    // (64,1001,2)
    const float* __restrict__ demands,   // (64,1001)
    const float* __restrict__ capacity,  // (64,)
    const uint8_t* __restrict__ assign,  // (64,1000)
    const float* __restrict__ slp,       // (64,1000)
    double* __restrict__ pdist,          // (256,) per-block partials
    double* __restrict__ lp,             // (64,)
    int* __restrict__ counter,           // (1,) zeroed before launch
    float* __restrict__ out) {           // (2,)
  int b = blockIdx.x >> 2;               // instance
  int sb = blockIdx.x & 3;               // sub-block within instance
  int tid = threadIdx.x;
  int lane = tid & 63, wv = tid >> 6;

  __shared__ float memx[NC], memy[NC], memd[NC];
  __shared__ uint16_t rs_[NC], rl_[NC];
  __shared__ uint32_t grt[MAXR];
  __shared__ int wsum[NW][KC];
  __shared__ int woff[NW][KC];
  __shared__ int mc[KC], mbase[KC], rc[KC], rbase[KC];
  __shared__ int rtot_s;
  __shared__ int is_last;
  __shared__ double dred[NW];

  // ---- entry loads ----
  const float* cb = coords + (size_t)b * 1001 * 2;
  int i0 = tid * 4;
  bool valid = (i0 < NC);                // NC % 4 == 0: chunk all-in/all-out
  int a0 = 0xFF, a1 = 0xFF, a2 = 0xFF, a3 = 0xFF;
  float x0f = 0, y0f = 0, d0f = 0, x1f = 0, y1f = 0, d1f = 0;
  float x2f = 0, y2f = 0, d2f = 0, x3f = 0, y3f = 0, d3f = 0;
  if (valid) {
    const float* db = demands + (size_t)b * 1001;
    const float2* cb2 = reinterpret_cast<const float2*>(cb);
    uchar4 av = *(const uchar4*)(assign + (size_t)b * NC + i0);
    a0 = av.x; a1 = av.y; a2 = av.z; a3 = av.w;
    float2 c0 = cb2[i0 + 1], c1 = cb2[i0 + 2], c2 = cb2[i0 + 3], c3 = cb2[i0 + 4];
    x0f = c0.x; y0f = c0.y; d0f = db[i0 + 1];
    x1f = c1.x; y1f = c1.y; d1f = db[i0 + 2];
    x2f = c2.x; y2f = c2.y; d2f = db[i0 + 3];
    x3f = c3.x; y3f = c3.y; d3f = db[i0 + 4];
  }
  float cap = capacity[b];
  float dx0 = cb[0], dy0 = cb[1];

  // ---- lp reduction (sb==0 only; same order as r10 -> bit-identical) ----
  {
    double lacc = 0.0;
    if (sb == 0)
      for (int n = tid; n < NC; n += BLK) lacc += (double)slp[(size_t)b * NC + n];
    double t = lacc;
#pragma unroll
    for (int m = 1; m < 64; m <<= 1) t += __shfl_xor(t, m);
    if (lane == 0) dred[wv] = t;
  }
  __syncthreads();
  if (tid == 0 && sb == 0) {
    double t = 0.0;
    for (int w = 0; w < NW; ++w) t += dred[w];
    lp[b] = t;
  }

  // ---- phase P: per-cluster wave scans ----
  int cnt[KC], excl[KC];
#pragma unroll
  for (int k = 0; k < KC; ++k)
    cnt[k] = (a0 == k) + (a1 == k) + (a2 == k) + (a3 == k);
#pragma unroll
  for (int k = 0; k < KC; ++k) {
    int x = cnt[k];
#pragma unroll
    for (int off = 1; off < 64; off <<= 1) {
      int v = __shfl_up(x, off);
      if (lane >= off) x += v;
    }
    if (lane == 63) wsum[wv][k] = x;
    excl[k] = x - cnt[k];                // exclusive rank within wave
  }
  __syncthreads();
  if (tid < KC) {
    int s = 0;
    for (int w = 0; w < NW; ++w) s += wsum[w][tid];
    mc[tid] = s;
  }
  __syncthreads();
  if (tid == 0) {
    int s = 0;
    for (int k = 0; k < KC; ++k) { mbase[k] = s; s += mc[k]; }
  }
  __syncthreads();
  if (tid < NW * KC) {
    int w = tid / KC, k = tid - w * KC;
    int s = mbase[k];
    for (int w2 = 0; w2 < w; ++w2) s += wsum[w2][k];
    woff[w][k] = s;
  }
  __syncthreads();

  // ---- stable scatter into member order ----
  if (valid) {
#pragma unroll
    for (int k = 0; k < KC; ++k) {
      int pos = woff[wv][k] + excl[k];
      if (a0 == k) { memx[pos] = x0f; memy[pos] = y0f; memd[pos] = d0f; pos++; }
      if (a1 == k) { memx[pos] = x1f; memy[pos] = y1f; memd[pos] = d1f; pos++; }
      if (a2 == k) { memx[pos] = x2f; memy[pos] = y2f; memd[pos] = d2f; pos++; }
      if (a3 == k) { memx[pos] = x3f; memy[pos] = y3f; memd[pos] = d3f; pos++; }
    }
  }
  __syncthreads();

  // ---- capacity split per cluster (exact f32 scan semantics) ----
  if (tid < KC) {
    int base = mbase[tid], M = mc[tid];
    int r = 0, cur = 0;
    float load = 0.0f;
    bool ne = false;
    for (int j0 = 0; j0 < M; j0 += 4) {
      float dd0 = memd[base + j0];
      float dd1 = (j0 + 1 < M) ? memd[base + j0 + 1] : 0.0f;
      float dd2 = (j0 + 2 < M) ? memd[base + j0 + 2] : 0.0f;
      float dd3 = (j0 + 3 < M) ? memd[base + j0 + 3] : 0.0f;
#define SPLIT_STEP(dd, jj)                                                    \
      if (j0 + jj < M) {                                                      \
        float d = dd;                                                         \
        if (ne && (load + d > cap)) {                                         \
          rs_[base + r] = (uint16_t)cur; rl_[base + r] = (uint16_t)(j0 + jj - cur); \
          r++; cur = j0 + jj; load = d;                                       \
        } else load += d;                                                     \
        ne = true;                                                            \
      }
      SPLIT_STEP(dd0, 0) SPLIT_STEP(dd1, 1) SPLIT_STEP(dd2, 2) SPLIT_STEP(dd3, 3)
#undef SPLIT_STEP
    }
    if (ne) { rs_[base + r] = (uint16_t)cur; rl_[base + r] = (uint16_t)(M - cur); r++; }
    rc[tid] = r;
  }
  __syncthreads();
  if (tid == 0) {
    int s = 0;
    for (int k = 0; k < KC; ++k) { rbase[k] = s; s += rc[k]; }
    rtot_s = (s < MAXR) ? s : MAXR;
  }
  __syncthreads();

  // ---- compact route table into LDS ----
  if (tid < KC) {
    int k = tid, base = mbase[k];
    for (int r = 0; r < rc[k]; ++r) {
      int slot = rbase[k] + r;
      if (slot < MAXR)
        grt[slot] =
            ((uint32_t)(base + rs_[base + r]) << 16) | (uint32_t)rl_[base + r];
    }
  }
  __syncthreads();

  // ---- phase NN: one 16-lane group per route ----
  int lane16 = tid & 15;
  int g = sb * (BLK / 16) + (tid >> 4);
  int R = rtot_s;
  double gacc = 0.0;

  for (int r = g; r < R; r += GPI) {
    uint32_t pk = grt[r];
    int start = (int)(pk >> 16);
    int L = (int)(pk & 0xFFFFu);

    float mx0 = 0, my0 = 0, mx1 = 0, my1 = 0, mx2 = 0, my2 = 0, mx3 = 0, my3 = 0;
    uint32_t vis = 0;
#define LOADC(c, MX, MY)                                                      \
    { int s = (c) * 16 + lane16;                                              \
      if (s < L) { MX = memx[start + s]; MY = memy[start + s]; }              \
      else vis |= (1u << (c)); }
    LOADC(0, mx0, my0) LOADC(1, mx1, my1) LOADC(2, mx2, my2) LOADC(3, mx3, my3)
#undef LOADC

    float px = dx0, py = dy0, racc = 0.0f;
    for (int step = 0; step < L; ++step) {
      float bd = INFINITY; int bc = -1; float bx = 0, by = 0;
#define CAND(c, MX, MY)                                                       \
      if (!(vis & (1u << (c)))) {                                             \
        float ddx = MX - px, ddy = MY - py;                                   \
        float d = sqrtf(ddx * ddx + ddy * ddy);                               \
        if (d < bd) { bd = d; bc = (c); bx = MX; by = MY; }                   \
      }
      CAND(0, mx0, my0) CAND(1, mx1, my1) CAND(2, mx2, my2) CAND(3, mx3, my3)
#undef CAND
      unsigned long long comb = (bc < 0)
          ? ~0ull
          : (((unsigned long long)__float_as_uint(bd)) << 32) |
            (unsigned)(bc * 16 + lane16);
      dpp_min_step<0xB1>(comb, bx, by);    // lane^1
      dpp_min_step<0x4E>(comb, bx, by);    // lane^2
      dpp_min_step<0x141>(comb, bx, by);   // half mirror
      dpp_min_step<0x140>(comb, bx, by);   // mirror
      int slot = (int)(comb & 0xFFFFFFFFull);
      float best = __uint_as_float((uint32_t)(comb >> 32));
      int src16 = slot & 15, cu = slot >> 4;
      if (src16 == lane16) vis |= (1u << cu);
      px = bx; py = by;
      racc += best;                        // f32, reference scan order
    }
    float ddx = px - dx0, ddy = py - dy0;
    racc += sqrtf(ddx * ddx + ddy * ddy);  // return-to-depot leg
    gacc += (double)racc;                  // racc uniform across group
  }

  // ---- block partial sum (wave butterfly + cross-wave, deterministic) ----
  {
    double t = (lane16 == 0) ? gacc : 0.0;
#pragma unroll
    for (int m = 1; m < 64; m <<= 1) t += __shfl_xor(t, m);
    if (lane == 0) dred[wv] = t;
  }
  __syncthreads();
  if (tid == 0) {
    double t = 0.0;
    for (int w = 0; w < NW; ++w) t += dred[w];
    pdist[blockIdx.x] = t;
  }

  // ---- last-block finalize (device-scope release/acquire, proven r7-r10) --
  if (tid == 0) {
    __threadfence();
    int old = atomicAdd(counter, 1);
    __threadfence();
    is_last = (old == (int)gridDim.x - 1);
  }
  __syncthreads();
  if (is_last) {
    __threadfence();
    if (tid < 64) {
      double dd = pdist[4 * tid] + pdist[4 * tid + 1] +
                  pdist[4 * tid + 2] + pdist[4 * tid + 3];
      float df = (float)dd;
      float lf = (float)lp[tid];
      double m = (double)df;
#pragma unroll
      for (int m2 = 1; m2 < 64; m2 <<= 1) m += __shfl_xor(m, m2);
      double mean = m / 64.0;
      float meanf = (float)mean;
      double li = ((double)df - (double)meanf) * (double)lf;
#pragma unroll
      for (int m2 = 1; m2 < 64; m2 <<= 1) li += __shfl_xor(li, m2);
      if (tid == 0) {
        out[0] = (float)(li / 64.0);
        out[1] = meanf;
      }
    }
  }
}

extern "C" void kernel_launch(void* const* d_in, const int* in_sizes, int n_in,
                              void* d_out, int out_size, void* d_ws, size_t ws_size,
                              hipStream_t stream) {
  const float* logits   = (const float*)d_in[0];  // (64,1001,10)
  const float* coords   = (const float*)d_in[1];  // (64,1001,2)
  const float* demands  = (const float*)d_in[2];  // (64,1001)
  const float* capacity = (const float*)d_in[3];  // (64,)

  uint8_t* ws = (uint8_t*)d_ws;
  double*  pdist   = (double*)(ws);           // 2048 B
  double*  lp      = (double*)(ws + 2048);    // 512 B
  int*     counter = (int*)(ws + 2560);       // 4 B (zeroed every call)
  uint8_t* assign  = (uint8_t*)(ws + 3072);   // 64000 B
  float*   slp     = (float*)(ws + 67072);    // 256000 B

  uint32_t ks0, ks1;
  threefry2x32(0u, 42u, 0u, 0u, &ks0, &ks1);   // fold_in(key(42), 0)

  hipMemsetAsync(counter, 0, sizeof(int), stream);
  k_sample<<<dim3((BB * NC + 255) / 256), dim3(256), 0, stream>>>(
      logits, ks0, ks1, assign, slp);
  k_fused<<<dim3(BB * WPI), dim3(BLK), 0, stream>>>(
      coords, demands, capacity, assign, slp,
      pdist, lp, counter, (float*)d_out);
}